// Round 6
// baseline (211.911 us; speedup 1.0000x reference)
//
#include <hip/hip_runtime.h>
#include <cstdint>
#include <cstddef>

#define DIMC 768
#define NHH  12
#define NSEQ 1024
#define HD   64

#define SX  6291456   // x elems (8*1024*768)
#define SW1 1769472   // qkv_w elems
#define SW2 589824    // proj_w elems

#define RELN 3969     // 63*63 table entries per head
#define RELP 4032     // padded stride

#define NCAST ((SX + SW1 + SW2) / 2048)       // 4224 cast blocks
#define NRELB ((NHH * RELN + 255) / 256)      // 187 relt blocks

typedef _Float16 f16x8 __attribute__((ext_vector_type(8)));
typedef _Float16 f16x4 __attribute__((ext_vector_type(4)));
typedef float    f32x4 __attribute__((ext_vector_type(4)));
typedef float    f32x16 __attribute__((ext_vector_type(16)));

__device__ inline void gld16(const void* g, void* l) {
  __builtin_amdgcn_global_load_lds(
      (const __attribute__((address_space(1))) void*)g,
      (__attribute__((address_space(3))) void*)l, 16, 0, 0);
}

// ---------------------------------------------------------------------------
// Fused fp32 -> fp16 cast of x | qkv_w | proj_w into one contiguous ws region,
// PLUS (tail blocks) the head-major fp32 relative-bias table transpose.
// ---------------------------------------------------------------------------
__global__ __launch_bounds__(256) void cast_f16(
    const float* __restrict__ x, const float* __restrict__ w1,
    const float* __restrict__ w2, _Float16* __restrict__ dst,
    const float* __restrict__ rel_table, float* __restrict__ relT) {
  if (blockIdx.x >= NCAST) {                  // relT transpose tail
    const int g = (blockIdx.x - NCAST) * 256 + threadIdx.x;
    if (g < NHH * RELN) {
      const int h = g / RELN, idx = g - h * RELN;
      relT[h * RELP + idx] = rel_table[idx * NHH + h];
    }
    return;
  }
  const long long t = (long long)blockIdx.x * 256 + threadIdx.x;
  const long long i = t * 8;
  const float* src; long long off;
  if (i < SX) { src = x; off = i; }
  else if (i < SX + SW1) { src = w1; off = i - SX; }
  else { src = w2; off = i - (SX + SW1); }
  const float4 a = *(const float4*)(src + off);
  const float4 b = *(const float4*)(src + off + 4);
  f16x8 o;
  o[0] = (_Float16)a.x; o[1] = (_Float16)a.y; o[2] = (_Float16)a.z; o[3] = (_Float16)a.w;
  o[4] = (_Float16)b.x; o[5] = (_Float16)b.y; o[6] = (_Float16)b.z; o[7] = (_Float16)b.w;
  *(f16x8*)(dst + i) = o;
}

// ---------------------------------------------------------------------------
// MFMA GEMM: C[m,o] = sum_k A[m,k]*W[o,k].  128x128 tile, BK=32.
// T3+T4+T2 stack (resubmit of round-4 source; round-4 bench was a container
// flake, and a full re-audit found no hang/fault mechanism: barriers uniform,
// per-wave vmcnt counts exact, bounds in range, gld_lds dests wave-uniform).
//  * 3 LDS buffers, 2-deep prefetch, raw s_barrier + COUNTED s_waitcnt
//    vmcnt(4) (vmcnt(0) only at the peeled last step).  Wait at step s
//    targets loads issued 2 compute phases (~500+cy) earlier.  Race-safe:
//    stage(s+2) overwrites the buffer last read at step s-1; the single
//    barrier at top of step s orders all waves past that compute.
//    sched_barrier(0) brackets stop hipcc migrating MFMA/ds_read across
//    the asm waitcnt/barrier (rule #18).  Buffer indices compile-time
//    (manual 3-unroll, macros not lambdas).
//  * T2 chunk swizzle slot = chunk ^ ((row>>1)&3): rows 0..7 cover all 8
//    bank-quads -> 2-way (free) instead of 8-way ds_read conflict.
//    Write side: gld_lds linear dest + inverse-permuted global source
//    (involution, within-row -> coalescing intact).
// ---------------------------------------------------------------------------
#define GSTAGE(K0, TGT)                               \
  {                                                   \
    const int kk = (K0);                              \
    gld16(Ap0 + kk, &Alds[TGT][c0 * 8]);              \
    gld16(Ap1 + kk, &Alds[TGT][c1 * 8]);              \
    gld16(Wp0 + kk, &Blds[TGT][c0 * 8]);              \
    gld16(Wp1 + kk, &Blds[TGT][c1 * 8]);              \
  }

#define GCOMP(CUR)                                                             \
  {                                                                            \
    f16x8 a[4], b[4];                                                          \
    _Pragma("unroll") for (int i = 0; i < 4; i++)                              \
      a[i] = *(const f16x8*)&Alds[CUR][(wr + i * 16 + l16) * 32 + rchunk * 8]; \
    _Pragma("unroll") for (int j = 0; j < 4; j++)                              \
      b[j] = *(const f16x8*)&Blds[CUR][(wc + j * 16 + l16) * 32 + rchunk * 8]; \
    _Pragma("unroll") for (int i = 0; i < 4; i++)                              \
      _Pragma("unroll") for (int j = 0; j < 4; j++)                            \
        acc[i][j] =                                                            \
            __builtin_amdgcn_mfma_f32_16x16x32_f16(a[i], b[j], acc[i][j], 0, 0, 0); \
  }

#define GSYNC4                                        \
  __builtin_amdgcn_sched_barrier(0);                  \
  asm volatile("s_waitcnt vmcnt(4)" ::: "memory");    \
  __builtin_amdgcn_s_barrier();                       \
  __builtin_amdgcn_sched_barrier(0);

#define GSYNC0                                        \
  __builtin_amdgcn_sched_barrier(0);                  \
  asm volatile("s_waitcnt vmcnt(0)" ::: "memory");    \
  __builtin_amdgcn_s_barrier();                       \
  __builtin_amdgcn_sched_barrier(0);

template <int EPI>
__global__ __launch_bounds__(256) void gemm_mfma(
    const _Float16* __restrict__ A, const _Float16* __restrict__ W,
    const float* __restrict__ b0, const float* __restrict__ b1,
    float* __restrict__ outF, _Float16* __restrict__ oq,
    _Float16* __restrict__ ok, _Float16* __restrict__ ovt) {
  __shared__ _Float16 Alds[3][128 * 32];
  __shared__ _Float16 Blds[3][128 * 32];

  const int tid = threadIdx.x;
  const int w = tid >> 6, lane = tid & 63, quad = lane >> 4, l16 = lane & 15;
  const int m0 = (blockIdx.x & 63) << 7;
  const int o0 = (blockIdx.x >> 6) << 7;
  const int wr = (w >> 1) * 64, wc = (w & 1) * 64;
  const int rchunk = quad ^ ((l16 >> 1) & 3);   // T2 swizzled read chunk

  f32x4 acc[4][4];
#pragma unroll
  for (int i = 0; i < 4; i++)
#pragma unroll
    for (int j = 0; j < 4; j++) acc[i][j] = (f32x4){0.f, 0.f, 0.f, 0.f};

  // staging: thread owns LDS 16B slots c0=tid, c1=tid+256 (linear dest);
  // global source chunk inverse-permuted by the same involution.
  const int c0 = tid, c1 = 256 + tid;
  const int r0 = c0 >> 2, r1 = c1 >> 2;
  const int g0 = ((c0 & 3) ^ ((r0 >> 1) & 3)) * 8;
  const int g1 = ((c1 & 3) ^ ((r1 >> 1) & 3)) * 8;
  const _Float16* Ap0 = A + (size_t)(m0 + r0) * DIMC + g0;
  const _Float16* Ap1 = A + (size_t)(m0 + r1) * DIMC + g1;
  const _Float16* Wp0 = W + (size_t)(o0 + r0) * DIMC + g0;
  const _Float16* Wp1 = W + (size_t)(o0 + r1) * DIMC + g1;

  GSTAGE(0, 0);                               // prologue: 2-deep
  GSTAGE(32, 1);

  for (int sb = 0; sb < 24; sb += 3) {
    // step sb+0: compute buf0, stage -> buf2
    GSYNC4;
    if (sb + 2 < 24) GSTAGE((sb + 2) * 32, 2);
    GCOMP(0);
    // step sb+1: compute buf1, stage -> buf0
    GSYNC4;
    if (sb + 3 < 24) GSTAGE((sb + 3) * 32, 0);
    GCOMP(1);
    // step sb+2: compute buf2, stage -> buf1
    if (sb + 2 == 23) { GSYNC0; }
    else              { GSYNC4; }
    if (sb + 4 < 24) GSTAGE((sb + 4) * 32, 1);
    GCOMP(2);
  }

  if constexpr (EPI == 0) {
#pragma unroll
    for (int j = 0; j < 4; j++) {
      const int o = o0 + wc + j * 16 + l16;
      const int part = o / DIMC;
      const int cc = o - part * DIMC;
      const int hh = cc >> 6, d = cc & 63;
      const float badd = (part == 0) ? b0[cc] : (part == 2 ? b1[cc] : 0.f);
      if (part == 2) {
        // V: write transposed into Vt[bh][d][n], f16x4 along n
#pragma unroll
        for (int i = 0; i < 4; i++) {
          const int mb = m0 + wr + i * 16 + quad * 4;
          const int bb = mb >> 10, n0 = mb & 1023;
          f16x4 vv;
#pragma unroll
          for (int r = 0; r < 4; r++) vv[r] = (_Float16)(acc[i][j][r] + badd);
          *(f16x4*)(ovt + (((size_t)(bb * NHH + hh)) * HD + d) * NSEQ + n0) = vv;
        }
      } else {
        _Float16* dst = (part == 0) ? oq : ok;
#pragma unroll
        for (int i = 0; i < 4; i++) {
#pragma unroll
          for (int r = 0; r < 4; r++) {
            const int m = m0 + wr + i * 16 + quad * 4 + r;
            const int bb = m >> 10, n = m & 1023;
            float v = acc[i][j][r];
            if (part == 0) v = (v + badd) * 0.125f;
            dst[(((size_t)(bb * NHH + hh)) * NSEQ + n) * HD + d] = (_Float16)v;
          }
        }
      }
    }
  } else {
#pragma unroll
    for (int j = 0; j < 4; j++) {
      const int o = o0 + wc + j * 16 + l16;
      const float bo = b0[o];
#pragma unroll
      for (int i = 0; i < 4; i++) {
#pragma unroll
        for (int r = 0; r < 4; r++) {
          const int m = m0 + wr + i * 16 + quad * 4 + r;
          outF[(size_t)m * DIMC + o] = acc[i][j][r] + bo;
        }
      }
    }
  }
}

// ---------------------------------------------------------------------------
// Flash attention, 32x32x16 MFMA transposed compute (S^T = K Q^T, O^T = V^T P^T).
// KVBLK=64 + LDS double-buffer, single barrier per step; bias rows staged to
// LDS; register-free staging (inverse-swizzle gld_lds).  Unchanged (verified
// r11: 65 -> <56 us; per-step compute ~1100cy covers 1-step-ahead latency).
// ---------------------------------------------------------------------------
__global__ __launch_bounds__(256, 3) void flash_mfma(
    const _Float16* __restrict__ Qg, const _Float16* __restrict__ Kg,
    const _Float16* __restrict__ Vtg, const float* __restrict__ relT,
    _Float16* __restrict__ AO) {
  const int nblk = blockIdx.x;
  const int bhl = nblk % 96;                  // same-XCD group key
  const int qt = nblk / 96;                   // 0..7 (128 q rows each)
  const int head = bhl >> 3, b = bhl & 7;
  const int bh = b * NHH + head;
  const int tid = threadIdx.x, w = tid >> 6, lane = tid & 63;
  const int ql = lane & 31;                   // q column within wave tile
  const int hf = lane >> 5;                   // lane half (k/d sub-offset)

  // double-buffered K/V tiles (KVBLK=64): 2 x (8+8) KB = 32 KB
  __shared__ _Float16 Klds[2][64 * 64];       // [row][chunk^key], 8 chunks/row
  __shared__ _Float16 Vlds[2][64 * 64];       // [d-row][chunk^key], 8 chunks/row
  __shared__ __attribute__((aligned(16))) float BiasLds[2][320];  // 5 rows x 63 + pad

  // persistent Q B-frags: B[n=ql][k = s*16 + hf*8 + j]
  const int qglob = qt * 128 + w * 32 + ql;
  const _Float16* Qrow = Qg + ((size_t)bh * NSEQ + qglob) * HD + hf * 8;
  f16x8 bq[4];
#pragma unroll
  for (int s = 0; s < 4; s++) bq[s] = *(const f16x8*)(Qrow + s * 16);

  f32x16 O0 = {}, O1 = {};                    // O^T d-tiles 0..31, 32..63
  float psum = 0.f;

  const _Float16* Kbase = Kg + (size_t)bh * NSEQ * HD;
  const _Float16* Vtbase = Vtg + (size_t)bh * HD * NSEQ;

  // bias: qy fixed per wave; dy = qy - tau + 31, tau = 2*step + t
  const float* relTh = relT + (size_t)head * RELP;
  const int idxb = ql + 31 - 4 * hf;          // dx = idxb - (r&3) - 8*(r>>2)

  // V A-frag row keys (fixed per lane)
  const int vrow0 = ql, vrow1 = 32 + ql;
  const int vkey0 = (vrow0 ^ (vrow0 >> 3)) & 7;
  const int vkey1 = (vrow1 ^ (vrow1 >> 3)) & 7;

  // staging: inverse-swizzled global offsets, linear LDS dest (involution).
  int ks0, ks1, vs0, vs1;
  {
    int c = tid;
    int r = c >> 3, cc = c & 7, key = (r ^ (r >> 3)) & 7;
    ks0 = r * HD + (cc ^ key) * 8;
    vs0 = r * NSEQ + (cc ^ key) * 8;
    c = tid + 256;
    r = c >> 3; cc = c & 7; key = (r ^ (r >> 3)) & 7;
    ks1 = r * HD + (cc ^ key) * 8;
    vs1 = r * NSEQ + (cc ^ key) * 8;
  }

  // stage step s into buffer bsel (K 8KB + V 8KB + bias 316 floats)
  auto stage = [&](int s, int bsel) {
    const _Float16* Ks = Kbase + (size_t)s * 64 * HD;
    const _Float16* Vs = Vtbase + s * 64;
    gld16(Ks + ks0, &Klds[bsel][tid * 8]);
    gld16(Ks + ks1, &Klds[bsel][(tid + 256) * 8]);
    gld16(Vs + vs0, &Vlds[bsel][tid * 8]);
    gld16(Vs + vs1, &Vlds[bsel][(tid + 256) * 8]);
    if (tid < 79) {                           // 79*4 = 316 floats, contiguous
      const int dyLo = qt * 4 + 30 - 2 * s;   // in [0, 58]; span <= RELP pad
      gld16(relTh + dyLo * 63 + tid * 4, &BiasLds[bsel][tid * 4]);
    }
  };

  stage(0, 0);                                // prologue (only exposed latency)

  int cur = 0;
#pragma unroll 2
  for (int s = 0; s < 16; s++) {
    __syncthreads();                          // drains own vmcnt -> buf[cur] ready
    if (s + 1 < 16) stage(s + 1, cur ^ 1);    // in flight under compute(s)

#pragma unroll
    for (int t = 0; t < 2; t++) {
      // S^T 32x32 tile: A = K rows (t*32+ql), contraction d (64)
      const int arow = t * 32 + ql;
      const int akey = (arow ^ (arow >> 3)) & 7;
      f32x16 S = {};
      __builtin_amdgcn_s_setprio(1);
#pragma unroll
      for (int ss = 0; ss < 4; ss++) {
        const f16x8 ak = *(const f16x8*)&Klds[cur][((arow << 3) | ((ss * 2 + hf) ^ akey)) * 8];
        S = __builtin_amdgcn_mfma_f32_32x32x16_f16(ak, bq[ss], S, 0, 0, 0);
      }
      __builtin_amdgcn_s_setprio(0);

      // bias from LDS (row = w+1-t, conflict-free lane-consecutive reads)
      // p_j of group g adds relT row entry [idxb - 8g - j]
      const float* lb = &BiasLds[cur][(w + 1 - t) * 63 + idxb];
      unsigned int dw[8];
#pragma unroll
      for (int g = 0; g < 4; g++) {
        const float b0 = lb[-8 * g - 0];
        const float b1 = lb[-8 * g - 1];
        const float b2 = lb[-8 * g - 2];
        const float b3 = lb[-8 * g - 3];
        const float p0 = __expf(S[4 * g + 0] + b0);
        const float p1 = __expf(S[4 * g + 1] + b1);
        const float p2 = __expf(S[4 * g + 2] + b2);
        const float p3 = __expf(S[4 * g + 3] + b3);
        psum += (p0 + p1) + (p2 + p3);
        union { f16x4 h; unsigned int u[2]; } cv;
        cv.h[0] = (_Float16)p0; cv.h[1] = (_Float16)p1;
        cv.h[2] = (_Float16)p2; cv.h[3] = (_Float16)p3;
        dw[2 * g] = cv.u[0]; dw[2 * g + 1] = cv.u[1];
      }

      // PV: B-frag from P^T via half-exchange; A = V^T rows from LDS
      __builtin_amdgcn_s_setprio(1);
#pragma unroll
      for (int s2 = 0; s2 < 2; s2++) {
        const unsigned int x0 = hf ? dw[4 * s2 + 0] : dw[4 * s2 + 2];
        const unsigned int x1 = hf ? dw[4 * s2 + 1] : dw[4 * s2 + 3];
        const unsigned int y0 = (unsigned int)__shfl_xor((int)x0, 32, 64);
        const unsigned int y1 = (unsigned int)__shfl_xor((int)x1, 32, 64);
        union { unsigned int u[4]; f16x8 v; } bp;
        if (hf == 0) {
          bp.u[0] = dw[4 * s2 + 0]; bp.u[1] = dw[4 * s2 + 1];
          bp.u[2] = y0;             bp.u[3] = y1;
        } else {
          bp.u[0] = y0;             bp.u[1] = y1;
          bp.u[2] = dw[4 * s2 + 2]; bp.u[3] = dw[4 * s2 + 3];
        }
        const int kchunk = t * 4 + s2 * 2 + hf;
        const f16x8 av0 = *(const f16x8*)&Vlds[cur][((vrow0 << 3) | (kchunk ^ vkey0)) * 8];
        O0 = __builtin_amdgcn_mfma_f32_32x32x16_f16(av0, bp.v, O0, 0, 0, 0);
        const f16x8 av1 = *(const f16x8*)&Vlds[cur][((vrow1 << 3) | (kchunk ^ vkey1)) * 8];
        O1 = __builtin_amdgcn_mfma_f32_32x32x16_f16(av1, bp.v, O1, 0, 0, 0);
      }
      __builtin_amdgcn_s_setprio(0);
    }
    cur ^= 1;
  }

  // total row-sum for this lane's q column; divide + store O^T
  psum += __shfl_xor(psum, 32, 64);
  const float inv = 1.f / psum;
  _Float16* aoRow = AO + ((size_t)(b * NSEQ + qglob)) * DIMC + head * HD;
#pragma unroll
  for (int g = 0; g < 4; g++) {
    f16x4 o0, o1;
#pragma unroll
    for (int j = 0; j < 4; j++) {
      o0[j] = (_Float16)(O0[4 * g + j] * inv);
      o1[j] = (_Float16)(O1[4 * g + j] * inv);
    }
    const int d0 = 8 * g + 4 * hf;
    *(f16x4*)(aoRow + d0) = o0;
    *(f16x4*)(aoRow + 32 + d0) = o1;
  }
}

extern "C" void kernel_launch(void* const* d_in, const int* in_sizes, int n_in,
                              void* d_out, int out_size, void* d_ws, size_t ws_size,
                              hipStream_t stream) {
  const float* x        = (const float*)d_in[0];
  const float* qkv_w    = (const float*)d_in[1];
  const float* q_bias   = (const float*)d_in[2];
  const float* v_bias   = (const float*)d_in[3];
  const float* proj_w   = (const float*)d_in[4];
  const float* proj_b   = (const float*)d_in[5];
  const float* rel_tab  = (const float*)d_in[6];
  float* out = (float*)d_out;

  const size_t NTOK = (size_t)8 * NHH * NSEQ * HD;
  _Float16* Xb     = (_Float16*)d_ws;
  _Float16* Wqkvb  = Xb + SX;
  _Float16* Wprojb = Wqkvb + SW1;
  _Float16* Qb     = Wprojb + SW2;
  _Float16* Kb     = Qb + NTOK;
  _Float16* Vt     = Kb + NTOK;             // V written transposed by qkv gemm
  float*    relT   = (float*)(Vt + NTOK);   // 12*4032 fp32 = 193 KB
  _Float16* AOb    = Xb;                    // alias: x consumed before flash writes

  cast_f16<<<dim3(NCAST + NRELB), 256, 0, stream>>>(x, qkv_w, proj_w, Xb,
                                                    rel_tab, relT);

  gemm_mfma<0><<<dim3(64 * 18), 256, 0, stream>>>(
      Xb, Wqkvb, q_bias, v_bias, nullptr, Qb, Kb, Vt);

  flash_mfma<<<dim3(768), 256, 0, stream>>>(Qb, Kb, Vt, relT, AOb);

  gemm_mfma<1><<<dim3(64 * 6), 256, 0, stream>>>(
      AOb, Wprojb, proj_b, nullptr, out, nullptr, nullptr, nullptr);
}

// Round 7
// 205.448 us; speedup vs baseline: 1.0315x; 1.0315x over previous
//
#include <hip/hip_runtime.h>
#include <cstdint>
#include <cstddef>

#define DIMC 768
#define NHH  12
#define NSEQ 1024
#define HD   64

#define SX  6291456   // x elems (8*1024*768)
#define SW1 1769472   // qkv_w elems
#define SW2 589824    // proj_w elems

#define RELN 3969     // 63*63 table entries per head
#define RELP 4032     // padded stride

#define NCAST ((SX + SW1 + SW2) / 2048)       // 4224 cast blocks
#define NRELB ((NHH * RELN + 255) / 256)      // 187 relt blocks

typedef _Float16 f16x8 __attribute__((ext_vector_type(8)));
typedef _Float16 f16x4 __attribute__((ext_vector_type(4)));
typedef float    f32x4 __attribute__((ext_vector_type(4)));
typedef float    f32x16 __attribute__((ext_vector_type(16)));

__device__ inline void gld16(const void* g, void* l) {
  __builtin_amdgcn_global_load_lds(
      (const __attribute__((address_space(1))) void*)g,
      (__attribute__((address_space(3))) void*)l, 16, 0, 0);
}

// ---------------------------------------------------------------------------
// Fused fp32 -> fp16 cast of x | qkv_w | proj_w into one contiguous ws region,
// PLUS (tail blocks) the head-major fp32 relative-bias table transpose.
// ---------------------------------------------------------------------------
__global__ __launch_bounds__(256) void cast_f16(
    const float* __restrict__ x, const float* __restrict__ w1,
    const float* __restrict__ w2, _Float16* __restrict__ dst,
    const float* __restrict__ rel_table, float* __restrict__ relT) {
  if (blockIdx.x >= NCAST) {                  // relT transpose tail
    const int g = (blockIdx.x - NCAST) * 256 + threadIdx.x;
    if (g < NHH * RELN) {
      const int h = g / RELN, idx = g - h * RELN;
      relT[h * RELP + idx] = rel_table[idx * NHH + h];
    }
    return;
  }
  const long long t = (long long)blockIdx.x * 256 + threadIdx.x;
  const long long i = t * 8;
  const float* src; long long off;
  if (i < SX) { src = x; off = i; }
  else if (i < SX + SW1) { src = w1; off = i - SX; }
  else { src = w2; off = i - (SX + SW1); }
  const float4 a = *(const float4*)(src + off);
  const float4 b = *(const float4*)(src + off + 4);
  f16x8 o;
  o[0] = (_Float16)a.x; o[1] = (_Float16)a.y; o[2] = (_Float16)a.z; o[3] = (_Float16)a.w;
  o[4] = (_Float16)b.x; o[5] = (_Float16)b.y; o[6] = (_Float16)b.z; o[7] = (_Float16)b.w;
  *(f16x8*)(dst + i) = o;
}

// ---------------------------------------------------------------------------
// MFMA GEMM: C[m,o] = sum_k A[m,k]*W[o,k].  128x128 tile, BK=32.
// Round 14: REVERT to the r3 structure (single LDS buffer, two syncthreads,
// 16KB, compiler-scheduled) -- it measured 56.5us vs 60.9 (r12 2-phase) and
// 73.4 (r13 3-buf counted-vmcnt).  Ledger: source-level pipelining on this
// GEMM trades away the TLP that was already hiding latency (m97/m114/m141
// replicated in-pipeline).  KEEP only the r13 ingredient that verifiably
// worked: T2 chunk-involution swizzle (bank conflicts 3.54M -> 0):
//   LDS slot c=(row,chunkL) holds global chunk chunkL^((row>>1)&3);
//   read chunk = quad^((l16>>1)&3).  Lanes cover all 8 16B-granule sets,
//   2-way aliasing = free.  gld_lds keeps linear dest, swizzled SOURCE.
// 1-D grid, XCD-swizzled: m_idx = n & 63.
// EPI==0: scatter f16 Q(+bias,*0.125), K, V->Vt transposed.
// EPI==1: fp32 outF = acc + b0[o].
// ---------------------------------------------------------------------------
template <int EPI>
__global__ __launch_bounds__(256) void gemm_mfma(
    const _Float16* __restrict__ A, const _Float16* __restrict__ W,
    const float* __restrict__ b0, const float* __restrict__ b1,
    float* __restrict__ outF, _Float16* __restrict__ oq,
    _Float16* __restrict__ ok, _Float16* __restrict__ ovt) {
  __shared__ _Float16 Alds[128 * 32];
  __shared__ _Float16 Blds[128 * 32];

  const int tid = threadIdx.x;
  const int w = tid >> 6, lane = tid & 63, quad = lane >> 4, l16 = lane & 15;
  const int m0 = (blockIdx.x & 63) << 7;
  const int o0 = (blockIdx.x >> 6) << 7;
  const int wr = (w >> 1) * 64, wc = (w & 1) * 64;
  const int rchunk = quad ^ ((l16 >> 1) & 3);   // T2 swizzled read chunk

  f32x4 acc[4][4];
#pragma unroll
  for (int i = 0; i < 4; i++)
#pragma unroll
    for (int j = 0; j < 4; j++) acc[i][j] = (f32x4){0.f, 0.f, 0.f, 0.f};

  // staging: thread owns LDS 16B slots c0=tid, c1=tid+256 (linear dest);
  // global source chunk inverse-permuted by the same involution.
  const int c0 = tid, c1 = 256 + tid;
  const int r0 = c0 >> 2, r1 = c1 >> 2;
  const int g0 = ((c0 & 3) ^ ((r0 >> 1) & 3)) * 8;
  const int g1 = ((c1 & 3) ^ ((r1 >> 1) & 3)) * 8;
  const _Float16* Ap0 = A + (size_t)(m0 + r0) * DIMC + g0;
  const _Float16* Ap1 = A + (size_t)(m0 + r1) * DIMC + g1;
  const _Float16* Wp0 = W + (size_t)(o0 + r0) * DIMC + g0;
  const _Float16* Wp1 = W + (size_t)(o0 + r1) * DIMC + g1;

  for (int k0 = 0; k0 < DIMC; k0 += 32) {
    __syncthreads();
    gld16(Ap0 + k0, &Alds[c0 * 8]);
    gld16(Ap1 + k0, &Alds[c1 * 8]);
    gld16(Wp0 + k0, &Blds[c0 * 8]);
    gld16(Wp1 + k0, &Blds[c1 * 8]);
    __syncthreads();

    f16x8 a[4], b[4];
#pragma unroll
    for (int i = 0; i < 4; i++)
      a[i] = *(const f16x8*)&Alds[(wr + i * 16 + l16) * 32 + rchunk * 8];
#pragma unroll
    for (int j = 0; j < 4; j++)
      b[j] = *(const f16x8*)&Blds[(wc + j * 16 + l16) * 32 + rchunk * 8];
#pragma unroll
    for (int i = 0; i < 4; i++)
#pragma unroll
      for (int j = 0; j < 4; j++)
        acc[i][j] = __builtin_amdgcn_mfma_f32_16x16x32_f16(a[i], b[j], acc[i][j], 0, 0, 0);
  }

  if constexpr (EPI == 0) {
#pragma unroll
    for (int j = 0; j < 4; j++) {
      const int o = o0 + wc + j * 16 + l16;
      const int part = o / DIMC;
      const int cc = o - part * DIMC;
      const int hh = cc >> 6, d = cc & 63;
      const float badd = (part == 0) ? b0[cc] : (part == 2 ? b1[cc] : 0.f);
      if (part == 2) {
        // V: write transposed into Vt[bh][d][n], f16x4 along n
#pragma unroll
        for (int i = 0; i < 4; i++) {
          const int mb = m0 + wr + i * 16 + quad * 4;
          const int bb = mb >> 10, n0 = mb & 1023;
          f16x4 vv;
#pragma unroll
          for (int r = 0; r < 4; r++) vv[r] = (_Float16)(acc[i][j][r] + badd);
          *(f16x4*)(ovt + (((size_t)(bb * NHH + hh)) * HD + d) * NSEQ + n0) = vv;
        }
      } else {
        _Float16* dst = (part == 0) ? oq : ok;
#pragma unroll
        for (int i = 0; i < 4; i++) {
#pragma unroll
          for (int r = 0; r < 4; r++) {
            const int m = m0 + wr + i * 16 + quad * 4 + r;
            const int bb = m >> 10, n = m & 1023;
            float v = acc[i][j][r];
            if (part == 0) v = (v + badd) * 0.125f;
            dst[(((size_t)(bb * NHH + hh)) * NSEQ + n) * HD + d] = (_Float16)v;
          }
        }
      }
    }
  } else {
#pragma unroll
    for (int j = 0; j < 4; j++) {
      const int o = o0 + wc + j * 16 + l16;
      const float bo = b0[o];
#pragma unroll
      for (int i = 0; i < 4; i++) {
#pragma unroll
        for (int r = 0; r < 4; r++) {
          const int m = m0 + wr + i * 16 + quad * 4 + r;
          outF[(size_t)m * DIMC + o] = acc[i][j][r] + bo;
        }
      }
    }
  }
}

// ---------------------------------------------------------------------------
// Flash attention, 32x32x16 MFMA transposed compute (S^T = K Q^T, O^T = V^T P^T).
// KVBLK=64 + LDS double-buffer, single barrier per step; bias rows staged to
// LDS; register-free staging (inverse-swizzle gld_lds).  Unchanged (verified
// r11: 65 -> <56 us; per-step compute ~1100cy covers 1-step-ahead latency).
// ---------------------------------------------------------------------------
__global__ __launch_bounds__(256, 3) void flash_mfma(
    const _Float16* __restrict__ Qg, const _Float16* __restrict__ Kg,
    const _Float16* __restrict__ Vtg, const float* __restrict__ relT,
    _Float16* __restrict__ AO) {
  const int nblk = blockIdx.x;
  const int bhl = nblk % 96;                  // same-XCD group key
  const int qt = nblk / 96;                   // 0..7 (128 q rows each)
  const int head = bhl >> 3, b = bhl & 7;
  const int bh = b * NHH + head;
  const int tid = threadIdx.x, w = tid >> 6, lane = tid & 63;
  const int ql = lane & 31;                   // q column within wave tile
  const int hf = lane >> 5;                   // lane half (k/d sub-offset)

  // double-buffered K/V tiles (KVBLK=64): 2 x (8+8) KB = 32 KB
  __shared__ _Float16 Klds[2][64 * 64];       // [row][chunk^key], 8 chunks/row
  __shared__ _Float16 Vlds[2][64 * 64];       // [d-row][chunk^key], 8 chunks/row
  __shared__ __attribute__((aligned(16))) float BiasLds[2][320];  // 5 rows x 63 + pad

  // persistent Q B-frags: B[n=ql][k = s*16 + hf*8 + j]
  const int qglob = qt * 128 + w * 32 + ql;
  const _Float16* Qrow = Qg + ((size_t)bh * NSEQ + qglob) * HD + hf * 8;
  f16x8 bq[4];
#pragma unroll
  for (int s = 0; s < 4; s++) bq[s] = *(const f16x8*)(Qrow + s * 16);

  f32x16 O0 = {}, O1 = {};                    // O^T d-tiles 0..31, 32..63
  float psum = 0.f;

  const _Float16* Kbase = Kg + (size_t)bh * NSEQ * HD;
  const _Float16* Vtbase = Vtg + (size_t)bh * HD * NSEQ;

  // bias: qy fixed per wave; dy = qy - tau + 31, tau = 2*step + t
  const float* relTh = relT + (size_t)head * RELP;
  const int idxb = ql + 31 - 4 * hf;          // dx = idxb - (r&3) - 8*(r>>2)

  // V A-frag row keys (fixed per lane)
  const int vrow0 = ql, vrow1 = 32 + ql;
  const int vkey0 = (vrow0 ^ (vrow0 >> 3)) & 7;
  const int vkey1 = (vrow1 ^ (vrow1 >> 3)) & 7;

  // staging: inverse-swizzled global offsets, linear LDS dest (involution).
  int ks0, ks1, vs0, vs1;
  {
    int c = tid;
    int r = c >> 3, cc = c & 7, key = (r ^ (r >> 3)) & 7;
    ks0 = r * HD + (cc ^ key) * 8;
    vs0 = r * NSEQ + (cc ^ key) * 8;
    c = tid + 256;
    r = c >> 3; cc = c & 7; key = (r ^ (r >> 3)) & 7;
    ks1 = r * HD + (cc ^ key) * 8;
    vs1 = r * NSEQ + (cc ^ key) * 8;
  }

  // stage step s into buffer bsel (K 8KB + V 8KB + bias 316 floats)
  auto stage = [&](int s, int bsel) {
    const _Float16* Ks = Kbase + (size_t)s * 64 * HD;
    const _Float16* Vs = Vtbase + s * 64;
    gld16(Ks + ks0, &Klds[bsel][tid * 8]);
    gld16(Ks + ks1, &Klds[bsel][(tid + 256) * 8]);
    gld16(Vs + vs0, &Vlds[bsel][tid * 8]);
    gld16(Vs + vs1, &Vlds[bsel][(tid + 256) * 8]);
    if (tid < 79) {                           // 79*4 = 316 floats, contiguous
      const int dyLo = qt * 4 + 30 - 2 * s;   // in [0, 58]; span <= RELP pad
      gld16(relTh + dyLo * 63 + tid * 4, &BiasLds[bsel][tid * 4]);
    }
  };

  stage(0, 0);                                // prologue (only exposed latency)

  int cur = 0;
#pragma unroll 2
  for (int s = 0; s < 16; s++) {
    __syncthreads();                          // drains own vmcnt -> buf[cur] ready
    if (s + 1 < 16) stage(s + 1, cur ^ 1);    // in flight under compute(s)

#pragma unroll
    for (int t = 0; t < 2; t++) {
      // S^T 32x32 tile: A = K rows (t*32+ql), contraction d (64)
      const int arow = t * 32 + ql;
      const int akey = (arow ^ (arow >> 3)) & 7;
      f32x16 S = {};
      __builtin_amdgcn_s_setprio(1);
#pragma unroll
      for (int ss = 0; ss < 4; ss++) {
        const f16x8 ak = *(const f16x8*)&Klds[cur][((arow << 3) | ((ss * 2 + hf) ^ akey)) * 8];
        S = __builtin_amdgcn_mfma_f32_32x32x16_f16(ak, bq[ss], S, 0, 0, 0);
      }
      __builtin_amdgcn_s_setprio(0);

      // bias from LDS (row = w+1-t, conflict-free lane-consecutive reads)
      // p_j of group g adds relT row entry [idxb - 8g - j]
      const float* lb = &BiasLds[cur][(w + 1 - t) * 63 + idxb];
      unsigned int dw[8];
#pragma unroll
      for (int g = 0; g < 4; g++) {
        const float b0 = lb[-8 * g - 0];
        const float b1 = lb[-8 * g - 1];
        const float b2 = lb[-8 * g - 2];
        const float b3 = lb[-8 * g - 3];
        const float p0 = __expf(S[4 * g + 0] + b0);
        const float p1 = __expf(S[4 * g + 1] + b1);
        const float p2 = __expf(S[4 * g + 2] + b2);
        const float p3 = __expf(S[4 * g + 3] + b3);
        psum += (p0 + p1) + (p2 + p3);
        union { f16x4 h; unsigned int u[2]; } cv;
        cv.h[0] = (_Float16)p0; cv.h[1] = (_Float16)p1;
        cv.h[2] = (_Float16)p2; cv.h[3] = (_Float16)p3;
        dw[2 * g] = cv.u[0]; dw[2 * g + 1] = cv.u[1];
      }

      // PV: B-frag from P^T via half-exchange; A = V^T rows from LDS
      __builtin_amdgcn_s_setprio(1);
#pragma unroll
      for (int s2 = 0; s2 < 2; s2++) {
        const unsigned int x0 = hf ? dw[4 * s2 + 0] : dw[4 * s2 + 2];
        const unsigned int x1 = hf ? dw[4 * s2 + 1] : dw[4 * s2 + 3];
        const unsigned int y0 = (unsigned int)__shfl_xor((int)x0, 32, 64);
        const unsigned int y1 = (unsigned int)__shfl_xor((int)x1, 32, 64);
        union { unsigned int u[4]; f16x8 v; } bp;
        if (hf == 0) {
          bp.u[0] = dw[4 * s2 + 0]; bp.u[1] = dw[4 * s2 + 1];
          bp.u[2] = y0;             bp.u[3] = y1;
        } else {
          bp.u[0] = y0;             bp.u[1] = y1;
          bp.u[2] = dw[4 * s2 + 2]; bp.u[3] = dw[4 * s2 + 3];
        }
        const int kchunk = t * 4 + s2 * 2 + hf;
        const f16x8 av0 = *(const f16x8*)&Vlds[cur][((vrow0 << 3) | (kchunk ^ vkey0)) * 8];
        O0 = __builtin_amdgcn_mfma_f32_32x32x16_f16(av0, bp.v, O0, 0, 0, 0);
        const f16x8 av1 = *(const f16x8*)&Vlds[cur][((vrow1 << 3) | (kchunk ^ vkey1)) * 8];
        O1 = __builtin_amdgcn_mfma_f32_32x32x16_f16(av1, bp.v, O1, 0, 0, 0);
      }
      __builtin_amdgcn_s_setprio(0);
    }
    cur ^= 1;
  }

  // total row-sum for this lane's q column; divide + store O^T
  psum += __shfl_xor(psum, 32, 64);
  const float inv = 1.f / psum;
  _Float16* aoRow = AO + ((size_t)(b * NSEQ + qglob)) * DIMC + head * HD;
#pragma unroll
  for (int g = 0; g < 4; g++) {
    f16x4 o0, o1;
#pragma unroll
    for (int j = 0; j < 4; j++) {
      o0[j] = (_Float16)(O0[4 * g + j] * inv);
      o1[j] = (_Float16)(O1[4 * g + j] * inv);
    }
    const int d0 = 8 * g + 4 * hf;
    *(f16x4*)(aoRow + d0) = o0;
    *(f16x4*)(aoRow + 32 + d0) = o1;
  }
}

extern "C" void kernel_launch(void* const* d_in, const int* in_sizes, int n_in,
                              void* d_out, int out_size, void* d_ws, size_t ws_size,
                              hipStream_t stream) {
  const float* x        = (const float*)d_in[0];
  const float* qkv_w    = (const float*)d_in[1];
  const float* q_bias   = (const float*)d_in[2];
  const float* v_bias   = (const float*)d_in[3];
  const float* proj_w   = (const float*)d_in[4];
  const float* proj_b   = (const float*)d_in[5];
  const float* rel_tab  = (const float*)d_in[6];
  float* out = (float*)d_out;

  const size_t NTOK = (size_t)8 * NHH * NSEQ * HD;
  _Float16* Xb     = (_Float16*)d_ws;
  _Float16* Wqkvb  = Xb + SX;
  _Float16* Wprojb = Wqkvb + SW1;
  _Float16* Qb     = Wprojb + SW2;
  _Float16* Kb     = Qb + NTOK;
  _Float16* Vt     = Kb + NTOK;             // V written transposed by qkv gemm
  float*    relT   = (float*)(Vt + NTOK);   // 12*4032 fp32 = 193 KB
  _Float16* AOb    = Xb;                    // alias: x consumed before flash writes

  cast_f16<<<dim3(NCAST + NRELB), 256, 0, stream>>>(x, qkv_w, proj_w, Xb,
                                                    rel_tab, relT);

  gemm_mfma<0><<<dim3(64 * 18), 256, 0, stream>>>(
      Xb, Wqkvb, q_bias, v_bias, nullptr, Qb, Kb, Vt);

  flash_mfma<<<dim3(768), 256, 0, stream>>>(Qb, Kb, Vt, relT, AOb);

  gemm_mfma<1><<<dim3(64 * 6), 256, 0, stream>>>(
      AOb, Wprojb, proj_b, nullptr, out, nullptr, nullptr, nullptr);
}

// Round 8
// 201.675 us; speedup vs baseline: 1.0508x; 1.0187x over previous
//
#include <hip/hip_runtime.h>
#include <cstdint>
#include <cstddef>

#define DIMC 768
#define NHH  12
#define NSEQ 1024
#define HD   64

#define SX  6291456   // x elems (8*1024*768)
#define SW1 1769472   // qkv_w elems
#define SW2 589824    // proj_w elems

#define RELN 3969     // 63*63 table entries per head
#define RELP 4032     // padded stride

#define NCAST ((SX + SW1 + SW2) / 2048)       // 4224 cast blocks
#define NRELB ((NHH * RELN + 255) / 256)      // 187 relt blocks

typedef _Float16 f16x8 __attribute__((ext_vector_type(8)));
typedef _Float16 f16x4 __attribute__((ext_vector_type(4)));
typedef float    f32x4 __attribute__((ext_vector_type(4)));
typedef float    f32x16 __attribute__((ext_vector_type(16)));

__device__ inline void gld16(const void* g, void* l) {
  __builtin_amdgcn_global_load_lds(
      (const __attribute__((address_space(1))) void*)g,
      (__attribute__((address_space(3))) void*)l, 16, 0, 0);
}

// ---------------------------------------------------------------------------
// Fused fp32 -> fp16 cast of x | qkv_w | proj_w into one contiguous ws region,
// PLUS (tail blocks) the head-major fp32 relative-bias table transpose.
// ---------------------------------------------------------------------------
__global__ __launch_bounds__(256) void cast_f16(
    const float* __restrict__ x, const float* __restrict__ w1,
    const float* __restrict__ w2, _Float16* __restrict__ dst,
    const float* __restrict__ rel_table, float* __restrict__ relT) {
  if (blockIdx.x >= NCAST) {                  // relT transpose tail
    const int g = (blockIdx.x - NCAST) * 256 + threadIdx.x;
    if (g < NHH * RELN) {
      const int h = g / RELN, idx = g - h * RELN;
      relT[h * RELP + idx] = rel_table[idx * NHH + h];
    }
    return;
  }
  const long long t = (long long)blockIdx.x * 256 + threadIdx.x;
  const long long i = t * 8;
  const float* src; long long off;
  if (i < SX) { src = x; off = i; }
  else if (i < SX + SW1) { src = w1; off = i - SX; }
  else { src = w2; off = i - (SX + SW1); }
  const float4 a = *(const float4*)(src + off);
  const float4 b = *(const float4*)(src + off + 4);
  f16x8 o;
  o[0] = (_Float16)a.x; o[1] = (_Float16)a.y; o[2] = (_Float16)a.z; o[3] = (_Float16)a.w;
  o[4] = (_Float16)b.x; o[5] = (_Float16)b.y; o[6] = (_Float16)b.z; o[7] = (_Float16)b.w;
  *(f16x8*)(dst + i) = o;
}

// ---------------------------------------------------------------------------
// MFMA GEMM: C[m,o] = sum_k A[m,k]*W[o,k].  128x128 tile, BK=64 (round 15).
// r7 ledger: plain+swizzle 54.4us beats every pipelined variant (60.9/73.4);
// structure stays single-buffer two-barrier, compiler-scheduled.  This round
// halves the number of stall EVENTS instead: BK 32 -> 64 gives 12 K-steps
// (was 24), same bytes, ~2x compute issue per vmcnt-drain.  Staging key
// ((tid>>3)&7) is invariant across the 4 row-groups -> zero extra VALU;
// ks=0/1 halves reuse a[4]/b[4] frags -> register-flat.  LDS 32KB (5 blk/CU
// LDS-limit > 4.5 grid avg).  T2 swizzle generalized to 8 chunks:
//   LDS slot (row, ch) holds global chunk ch ^ (row&7);
//   read chunk = (ks*4+quad) ^ (l16&7); l16 / l16+8 alias 2-way = free.
// 1-D grid, XCD-swizzled: m_idx = n & 63.
// EPI==0: scatter f16 Q(+bias,*0.125), K, V->Vt transposed.
// EPI==1: fp32 outF = acc + b0[o].
// ---------------------------------------------------------------------------
template <int EPI>
__global__ __launch_bounds__(256) void gemm_mfma(
    const _Float16* __restrict__ A, const _Float16* __restrict__ W,
    const float* __restrict__ b0, const float* __restrict__ b1,
    float* __restrict__ outF, _Float16* __restrict__ oq,
    _Float16* __restrict__ ok, _Float16* __restrict__ ovt) {
  __shared__ _Float16 Alds[128 * 64];
  __shared__ _Float16 Blds[128 * 64];

  const int tid = threadIdx.x;
  const int w = tid >> 6, lane = tid & 63, quad = lane >> 4, l16 = lane & 15;
  const int m0 = (blockIdx.x & 63) << 7;
  const int o0 = (blockIdx.x >> 6) << 7;
  const int wr = (w >> 1) * 64, wc = (w & 1) * 64;
  const int rkey = l16 & 7;                   // read-side swizzle key

  f32x4 acc[4][4];
#pragma unroll
  for (int i = 0; i < 4; i++)
#pragma unroll
    for (int j = 0; j < 4; j++) acc[i][j] = (f32x4){0.f, 0.f, 0.f, 0.f};

  // staging: slot c = tid + k*256 (k=0..3) -> row = (tid>>3)+32k, chunk = tid&7.
  // Global source chunk = (tid&7) ^ (row&7); row&7 == (tid>>3)&7 for all k.
  const int srow = tid >> 3;
  const int sch = ((tid & 7) ^ (srow & 7)) * 8;
  const _Float16* Ap = A + (size_t)(m0 + srow) * DIMC + sch;
  const _Float16* Wp = W + (size_t)(o0 + srow) * DIMC + sch;
  _Float16* Adst = &Alds[tid * 8];
  _Float16* Bdst = &Blds[tid * 8];

  for (int k0 = 0; k0 < DIMC; k0 += 64) {
    __syncthreads();
#pragma unroll
    for (int k = 0; k < 4; k++) {
      gld16(Ap + k0 + k * 32 * DIMC, Adst + k * 2048);
      gld16(Wp + k0 + k * 32 * DIMC, Bdst + k * 2048);
    }
    __syncthreads();                          // vmcnt drained -> tile visible

#pragma unroll
    for (int ks = 0; ks < 2; ks++) {
      const int ch = (((ks << 2) + quad) ^ rkey) * 8;
      f16x8 a[4], b[4];
#pragma unroll
      for (int i = 0; i < 4; i++)
        a[i] = *(const f16x8*)&Alds[(wr + i * 16 + l16) * 64 + ch];
#pragma unroll
      for (int j = 0; j < 4; j++)
        b[j] = *(const f16x8*)&Blds[(wc + j * 16 + l16) * 64 + ch];
#pragma unroll
      for (int i = 0; i < 4; i++)
#pragma unroll
        for (int j = 0; j < 4; j++)
          acc[i][j] = __builtin_amdgcn_mfma_f32_16x16x32_f16(a[i], b[j], acc[i][j], 0, 0, 0);
    }
  }

  if constexpr (EPI == 0) {
#pragma unroll
    for (int j = 0; j < 4; j++) {
      const int o = o0 + wc + j * 16 + l16;
      const int part = o / DIMC;
      const int cc = o - part * DIMC;
      const int hh = cc >> 6, d = cc & 63;
      const float badd = (part == 0) ? b0[cc] : (part == 2 ? b1[cc] : 0.f);
      if (part == 2) {
        // V: write transposed into Vt[bh][d][n], f16x4 along n
#pragma unroll
        for (int i = 0; i < 4; i++) {
          const int mb = m0 + wr + i * 16 + quad * 4;
          const int bb = mb >> 10, n0 = mb & 1023;
          f16x4 vv;
#pragma unroll
          for (int r = 0; r < 4; r++) vv[r] = (_Float16)(acc[i][j][r] + badd);
          *(f16x4*)(ovt + (((size_t)(bb * NHH + hh)) * HD + d) * NSEQ + n0) = vv;
        }
      } else {
        _Float16* dst = (part == 0) ? oq : ok;
#pragma unroll
        for (int i = 0; i < 4; i++) {
#pragma unroll
          for (int r = 0; r < 4; r++) {
            const int m = m0 + wr + i * 16 + quad * 4 + r;
            const int bb = m >> 10, n = m & 1023;
            float v = acc[i][j][r];
            if (part == 0) v = (v + badd) * 0.125f;
            dst[(((size_t)(bb * NHH + hh)) * NSEQ + n) * HD + d] = (_Float16)v;
          }
        }
      }
    }
  } else {
#pragma unroll
    for (int j = 0; j < 4; j++) {
      const int o = o0 + wc + j * 16 + l16;
      const float bo = b0[o];
#pragma unroll
      for (int i = 0; i < 4; i++) {
#pragma unroll
        for (int r = 0; r < 4; r++) {
          const int m = m0 + wr + i * 16 + quad * 4 + r;
          outF[(size_t)m * DIMC + o] = acc[i][j][r] + bo;
        }
      }
    }
  }
}

// ---------------------------------------------------------------------------
// Flash attention, 32x32x16 MFMA transposed compute (S^T = K Q^T, O^T = V^T P^T).
// KVBLK=64 + LDS double-buffer, single barrier per step; bias rows staged to
// LDS; register-free staging (inverse-swizzle gld_lds).  Unchanged (verified
// r11: 65 -> <56 us; per-step compute ~1100cy covers 1-step-ahead latency).
// ---------------------------------------------------------------------------
__global__ __launch_bounds__(256, 3) void flash_mfma(
    const _Float16* __restrict__ Qg, const _Float16* __restrict__ Kg,
    const _Float16* __restrict__ Vtg, const float* __restrict__ relT,
    _Float16* __restrict__ AO) {
  const int nblk = blockIdx.x;
  const int bhl = nblk % 96;                  // same-XCD group key
  const int qt = nblk / 96;                   // 0..7 (128 q rows each)
  const int head = bhl >> 3, b = bhl & 7;
  const int bh = b * NHH + head;
  const int tid = threadIdx.x, w = tid >> 6, lane = tid & 63;
  const int ql = lane & 31;                   // q column within wave tile
  const int hf = lane >> 5;                   // lane half (k/d sub-offset)

  // double-buffered K/V tiles (KVBLK=64): 2 x (8+8) KB = 32 KB
  __shared__ _Float16 Klds[2][64 * 64];       // [row][chunk^key], 8 chunks/row
  __shared__ _Float16 Vlds[2][64 * 64];       // [d-row][chunk^key], 8 chunks/row
  __shared__ __attribute__((aligned(16))) float BiasLds[2][320];  // 5 rows x 63 + pad

  // persistent Q B-frags: B[n=ql][k = s*16 + hf*8 + j]
  const int qglob = qt * 128 + w * 32 + ql;
  const _Float16* Qrow = Qg + ((size_t)bh * NSEQ + qglob) * HD + hf * 8;
  f16x8 bq[4];
#pragma unroll
  for (int s = 0; s < 4; s++) bq[s] = *(const f16x8*)(Qrow + s * 16);

  f32x16 O0 = {}, O1 = {};                    // O^T d-tiles 0..31, 32..63
  float psum = 0.f;

  const _Float16* Kbase = Kg + (size_t)bh * NSEQ * HD;
  const _Float16* Vtbase = Vtg + (size_t)bh * HD * NSEQ;

  // bias: qy fixed per wave; dy = qy - tau + 31, tau = 2*step + t
  const float* relTh = relT + (size_t)head * RELP;
  const int idxb = ql + 31 - 4 * hf;          // dx = idxb - (r&3) - 8*(r>>2)

  // V A-frag row keys (fixed per lane)
  const int vrow0 = ql, vrow1 = 32 + ql;
  const int vkey0 = (vrow0 ^ (vrow0 >> 3)) & 7;
  const int vkey1 = (vrow1 ^ (vrow1 >> 3)) & 7;

  // staging: inverse-swizzled global offsets, linear LDS dest (involution).
  int ks0, ks1, vs0, vs1;
  {
    int c = tid;
    int r = c >> 3, cc = c & 7, key = (r ^ (r >> 3)) & 7;
    ks0 = r * HD + (cc ^ key) * 8;
    vs0 = r * NSEQ + (cc ^ key) * 8;
    c = tid + 256;
    r = c >> 3; cc = c & 7; key = (r ^ (r >> 3)) & 7;
    ks1 = r * HD + (cc ^ key) * 8;
    vs1 = r * NSEQ + (cc ^ key) * 8;
  }

  // stage step s into buffer bsel (K 8KB + V 8KB + bias 316 floats)
  auto stage = [&](int s, int bsel) {
    const _Float16* Ks = Kbase + (size_t)s * 64 * HD;
    const _Float16* Vs = Vtbase + s * 64;
    gld16(Ks + ks0, &Klds[bsel][tid * 8]);
    gld16(Ks + ks1, &Klds[bsel][(tid + 256) * 8]);
    gld16(Vs + vs0, &Vlds[bsel][tid * 8]);
    gld16(Vs + vs1, &Vlds[bsel][(tid + 256) * 8]);
    if (tid < 79) {                           // 79*4 = 316 floats, contiguous
      const int dyLo = qt * 4 + 30 - 2 * s;   // in [0, 58]; span <= RELP pad
      gld16(relTh + dyLo * 63 + tid * 4, &BiasLds[bsel][tid * 4]);
    }
  };

  stage(0, 0);                                // prologue (only exposed latency)

  int cur = 0;
#pragma unroll 2
  for (int s = 0; s < 16; s++) {
    __syncthreads();                          // drains own vmcnt -> buf[cur] ready
    if (s + 1 < 16) stage(s + 1, cur ^ 1);    // in flight under compute(s)

#pragma unroll
    for (int t = 0; t < 2; t++) {
      // S^T 32x32 tile: A = K rows (t*32+ql), contraction d (64)
      const int arow = t * 32 + ql;
      const int akey = (arow ^ (arow >> 3)) & 7;
      f32x16 S = {};
      __builtin_amdgcn_s_setprio(1);
#pragma unroll
      for (int ss = 0; ss < 4; ss++) {
        const f16x8 ak = *(const f16x8*)&Klds[cur][((arow << 3) | ((ss * 2 + hf) ^ akey)) * 8];
        S = __builtin_amdgcn_mfma_f32_32x32x16_f16(ak, bq[ss], S, 0, 0, 0);
      }
      __builtin_amdgcn_s_setprio(0);

      // bias from LDS (row = w+1-t, conflict-free lane-consecutive reads)
      // p_j of group g adds relT row entry [idxb - 8g - j]
      const float* lb = &BiasLds[cur][(w + 1 - t) * 63 + idxb];
      unsigned int dw[8];
#pragma unroll
      for (int g = 0; g < 4; g++) {
        const float b0 = lb[-8 * g - 0];
        const float b1 = lb[-8 * g - 1];
        const float b2 = lb[-8 * g - 2];
        const float b3 = lb[-8 * g - 3];
        const float p0 = __expf(S[4 * g + 0] + b0);
        const float p1 = __expf(S[4 * g + 1] + b1);
        const float p2 = __expf(S[4 * g + 2] + b2);
        const float p3 = __expf(S[4 * g + 3] + b3);
        psum += (p0 + p1) + (p2 + p3);
        union { f16x4 h; unsigned int u[2]; } cv;
        cv.h[0] = (_Float16)p0; cv.h[1] = (_Float16)p1;
        cv.h[2] = (_Float16)p2; cv.h[3] = (_Float16)p3;
        dw[2 * g] = cv.u[0]; dw[2 * g + 1] = cv.u[1];
      }

      // PV: B-frag from P^T via half-exchange; A = V^T rows from LDS
      __builtin_amdgcn_s_setprio(1);
#pragma unroll
      for (int s2 = 0; s2 < 2; s2++) {
        const unsigned int x0 = hf ? dw[4 * s2 + 0] : dw[4 * s2 + 2];
        const unsigned int x1 = hf ? dw[4 * s2 + 1] : dw[4 * s2 + 3];
        const unsigned int y0 = (unsigned int)__shfl_xor((int)x0, 32, 64);
        const unsigned int y1 = (unsigned int)__shfl_xor((int)x1, 32, 64);
        union { unsigned int u[4]; f16x8 v; } bp;
        if (hf == 0) {
          bp.u[0] = dw[4 * s2 + 0]; bp.u[1] = dw[4 * s2 + 1];
          bp.u[2] = y0;             bp.u[3] = y1;
        } else {
          bp.u[0] = y0;             bp.u[1] = y1;
          bp.u[2] = dw[4 * s2 + 2]; bp.u[3] = dw[4 * s2 + 3];
        }
        const int kchunk = t * 4 + s2 * 2 + hf;
        const f16x8 av0 = *(const f16x8*)&Vlds[cur][((vrow0 << 3) | (kchunk ^ vkey0)) * 8];
        O0 = __builtin_amdgcn_mfma_f32_32x32x16_f16(av0, bp.v, O0, 0, 0, 0);
        const f16x8 av1 = *(const f16x8*)&Vlds[cur][((vrow1 << 3) | (kchunk ^ vkey1)) * 8];
        O1 = __builtin_amdgcn_mfma_f32_32x32x16_f16(av1, bp.v, O1, 0, 0, 0);
      }
      __builtin_amdgcn_s_setprio(0);
    }
    cur ^= 1;
  }

  // total row-sum for this lane's q column; divide + store O^T
  psum += __shfl_xor(psum, 32, 64);
  const float inv = 1.f / psum;
  _Float16* aoRow = AO + ((size_t)(b * NSEQ + qglob)) * DIMC + head * HD;
#pragma unroll
  for (int g = 0; g < 4; g++) {
    f16x4 o0, o1;
#pragma unroll
    for (int j = 0; j < 4; j++) {
      o0[j] = (_Float16)(O0[4 * g + j] * inv);
      o1[j] = (_Float16)(O1[4 * g + j] * inv);
    }
    const int d0 = 8 * g + 4 * hf;
    *(f16x4*)(aoRow + d0) = o0;
    *(f16x4*)(aoRow + 32 + d0) = o1;
  }
}

extern "C" void kernel_launch(void* const* d_in, const int* in_sizes, int n_in,
                              void* d_out, int out_size, void* d_ws, size_t ws_size,
                              hipStream_t stream) {
  const float* x        = (const float*)d_in[0];
  const float* qkv_w    = (const float*)d_in[1];
  const float* q_bias   = (const float*)d_in[2];
  const float* v_bias   = (const float*)d_in[3];
  const float* proj_w   = (const float*)d_in[4];
  const float* proj_b   = (const float*)d_in[5];
  const float* rel_tab  = (const float*)d_in[6];
  float* out = (float*)d_out;

  const size_t NTOK = (size_t)8 * NHH * NSEQ * HD;
  _Float16* Xb     = (_Float16*)d_ws;
  _Float16* Wqkvb  = Xb + SX;
  _Float16* Wprojb = Wqkvb + SW1;
  _Float16* Qb     = Wprojb + SW2;
  _Float16* Kb     = Qb + NTOK;
  _Float16* Vt     = Kb + NTOK;             // V written transposed by qkv gemm
  float*    relT   = (float*)(Vt + NTOK);   // 12*4032 fp32 = 193 KB
  _Float16* AOb    = Xb;                    // alias: x consumed before flash writes

  cast_f16<<<dim3(NCAST + NRELB), 256, 0, stream>>>(x, qkv_w, proj_w, Xb,
                                                    rel_tab, relT);

  gemm_mfma<0><<<dim3(64 * 18), 256, 0, stream>>>(
      Xb, Wqkvb, q_bias, v_bias, nullptr, Qb, Kb, Vt);

  flash_mfma<<<dim3(768), 256, 0, stream>>>(Qb, Kb, Vt, relT, AOb);

  gemm_mfma<1><<<dim3(64 * 6), 256, 0, stream>>>(
      AOb, Wprojb, proj_b, nullptr, out, nullptr, nullptr, nullptr);
}